// Round 13
// baseline (1293.221 us; speedup 1.0000x reference)
//
#include <hip/hip_runtime.h>
#include <hip/hip_bf16.h>

#define DEV __device__ __forceinline__

typedef short bf16x8 __attribute__((ext_vector_type(8)));
typedef float f32x16 __attribute__((ext_vector_type(16)));
typedef unsigned short u16x2 __attribute__((ext_vector_type(2)));

static constexpr int FDIM = 64;
static constexpr int HH   = 128;
static constexpr int NW   = 8;              // waves per block
static constexpr int TM   = NW * 32;        // 256 edges per block
static constexpr int CH   = 4096;           // weight chunk bytes: 128 n x 2 halves x 16B
static constexpr int NCH  = 27;             // 9 chunks x 3 layers (K=144, bias folded)
static constexpr int WT_ELEMS = NCH * 2048; // 55296 bf16 elements

static constexpr int PROW = 68;             // partial row stride (dwords, 272B: 64 data + pad)
static constexpr int NROW = 2 * NW;         // 16 partial rows

DEV unsigned pack2(float a, float b) {
    union { __hip_bfloat162 h; unsigned u; } cv;
    cv.h.x = __float2bfloat16(a);
    cv.h.y = __float2bfloat16(b);
    return cv.u;
}
DEV unsigned short f2bf(float f) {
    union { __hip_bfloat16 h; unsigned short u; } cv;
    cv.h = __float2bfloat16(f);
    return cv.u;
}
// packed bf16 max (valid for non-negative values: bit pattern is monotone)
DEV unsigned pmax2(unsigned a, unsigned b) {
    u16x2 av = __builtin_bit_cast(u16x2, a);
    u16x2 bv = __builtin_bit_cast(u16x2, b);
    return __builtin_bit_cast(unsigned, __builtin_elementwise_max(av, bv));
}
template <int CTRL>
DEV int dppmov(int x) {  // invalid lanes keep own value (old = x, bound_ctrl = false)
    return __builtin_amdgcn_update_dpp(x, x, CTRL, 0xf, 0xf, false);
}

// ---------------- input bf16 conversion ----------------
__global__ void k_cvt(const float* __restrict__ src, unsigned short* __restrict__ dst, int n8) {
    int i = blockIdx.x * 256 + threadIdx.x;
    if (i < n8) {
        float4 a = *(const float4*)(src + (size_t)i * 8);
        float4 b = *(const float4*)(src + (size_t)i * 8 + 4);
        uint4 o;
        o.x = pack2(a.x, a.y); o.y = pack2(a.z, a.w);
        o.z = pack2(b.x, b.y); o.w = pack2(b.z, b.w);
        *(uint4*)(dst + (size_t)i * 8) = o;
    }
}

// ---- weights -> chunk-major bf16 image (coalesced A-frag reads), bias folded ----
__global__ void k_wprep(const float* __restrict__ W1, const float* __restrict__ b1,
                        const float* __restrict__ W2, const float* __restrict__ b2,
                        const float* __restrict__ W3, const float* __restrict__ b3,
                        unsigned short* __restrict__ wt) {
    int i = blockIdx.x * 256 + threadIdx.x;
    if (i >= WT_ELEMS) return;
    int c = i >> 11, r = i & 2047;
    int n = r >> 4, half = (r >> 3) & 1, e = r & 7;
    int layer = c / 9, ks = c % 9;
    int k = ks * 16 + half * 8 + e;
    float v = 0.f;
    if (layer == 0) {
        if (k < 131) v = W1[k * HH + n];
        else if (k == 131) v = b1[n];        // msg feature 131 == 1.0
    } else {
        const float* W = (layer == 1) ? W2 : W3;
        const float* b = (layer == 1) ? b2 : b3;
        if (k < 128) v = W[k * HH + n];
        else if (k == 128) v = b[n];         // h feature 128 == 1.0
    }
    wt[i] = f2bf(v);
}

// ---------------- CSR build: hist -> scan -> fill ----------------
__global__ void k_hist(const int* __restrict__ edst, int* __restrict__ cnt, int E) {
    int e = blockIdx.x * 256 + threadIdx.x;
    if (e < E) atomicAdd(&cnt[edst[e]], 1);
}

__global__ void k_scan_part(const int* __restrict__ cnt, int* __restrict__ partial, int n2) {
    __shared__ int sm[256];
    int t = threadIdx.x;
    int base = blockIdx.x * 1024 + t * 4;
    int s = 0;
#pragma unroll
    for (int j = 0; j < 4; j++) { int idx = base + j; if (idx < n2) s += cnt[idx]; }
    sm[t] = s; __syncthreads();
    for (int off = 128; off > 0; off >>= 1) {
        if (t < off) sm[t] += sm[t + off];
        __syncthreads();
    }
    if (t == 0) partial[blockIdx.x] = sm[0];
}

__global__ void k_scan_top(int* __restrict__ partial, int nb) {
    __shared__ int sm[256];
    int t = threadIdx.x;
    int v = (t < nb) ? partial[t] : 0;
    sm[t] = v; __syncthreads();
    for (int off = 1; off < 256; off <<= 1) {
        int add = (t >= off) ? sm[t - off] : 0;
        __syncthreads();
        sm[t] += add;
        __syncthreads();
    }
    if (t < nb) partial[t] = sm[t] - v;   // exclusive
}

__global__ void k_scan_down(const int* __restrict__ cnt, const int* __restrict__ partial,
                            int* __restrict__ cursor, int n2) {
    __shared__ int sm[256];
    int t = threadIdx.x;
    int base = blockIdx.x * 1024 + t * 4;
    int c[4]; int s = 0;
#pragma unroll
    for (int j = 0; j < 4; j++) { int idx = base + j; c[j] = (idx < n2) ? cnt[idx] : 0; s += c[j]; }
    sm[t] = s; __syncthreads();
    for (int off = 1; off < 256; off <<= 1) {
        int add = (t >= off) ? sm[t - off] : 0;
        __syncthreads();
        sm[t] += add;
        __syncthreads();
    }
    int run = partial[blockIdx.x] + (sm[t] - s);
#pragma unroll
    for (int j = 0; j < 4; j++) {
        int idx = base + j;
        if (idx < n2) cursor[idx] = run;
        run += c[j];
    }
}

__global__ void k_fill(const int* __restrict__ edst, const int* __restrict__ esrc,
                       int* __restrict__ cursor, int2* __restrict__ csr_sd, int E) {
    int e = blockIdx.x * 256 + threadIdx.x;
    if (e < E) {
        int d = edst[e];
        int p = atomicAdd(&cursor[d], 1);
        csr_sd[p] = make_int2(esrc[e], d);
    }
}

// ---------------- register-resident MLP ----------------
DEV f32x16 zerov() {
    f32x16 v;
#pragma unroll
    for (int i = 0; i < 16; i++) v[i] = 0.f;
    return v;
}
DEV float relu(float x) { return fmaxf(x, 0.f); }

DEV void layer_reg(const char* __restrict__ wl, const unsigned pkin[32],
                   unsigned pkout[32], int l31, int hh, unsigned biasw) {
    unsigned xv[16];
#pragma unroll
    for (int ks = 0; ks < 8; ks++) {
        unsigned t0 = hh ? pkin[4 * ks + 0] : pkin[4 * ks + 2];
        unsigned t1 = hh ? pkin[4 * ks + 1] : pkin[4 * ks + 3];
        xv[2 * ks + 0] = (unsigned)__shfl_xor((int)t0, 32, 64);
        xv[2 * ks + 1] = (unsigned)__shfl_xor((int)t1, 32, 64);
    }
#pragma unroll
    for (int rt = 0; rt < 4; rt++) {
        const char* arow = wl + (rt * 32 + l31) * 32 + hh * 16;
        f32x16 acc = zerov();
#pragma unroll
        for (int ks = 0; ks < 8; ks++) {
            union { unsigned u[4]; bf16x8 v; } B;
            B.u[0] = hh ? xv[2 * ks + 0]   : pkin[4 * ks + 0];
            B.u[1] = hh ? xv[2 * ks + 1]   : pkin[4 * ks + 1];
            B.u[2] = hh ? pkin[4 * ks + 2] : xv[2 * ks + 0];
            B.u[3] = hh ? pkin[4 * ks + 3] : xv[2 * ks + 1];
            bf16x8 A = *(const bf16x8*)(arow + ks * CH);
            acc = __builtin_amdgcn_mfma_f32_32x32x16_bf16(A, B.v, acc, 0, 0, 0);
        }
        {   // ks = 8: bias row (feature 128 = 1.0)
            union { unsigned u[4]; bf16x8 v; } B;
            B.u[0] = biasw; B.u[1] = 0u; B.u[2] = 0u; B.u[3] = 0u;
            bf16x8 A = *(const bf16x8*)(arow + 8 * CH);
            acc = __builtin_amdgcn_mfma_f32_32x32x16_bf16(A, B.v, acc, 0, 0, 0);
        }
#pragma unroll
        for (int g = 0; g < 4; g++) {
            pkout[8 * rt + 2 * g + 0] = pack2(relu(acc[4 * g + 0]), relu(acc[4 * g + 1]));
            pkout[8 * rt + 2 * g + 1] = pack2(relu(acc[4 * g + 2]), relu(acc[4 * g + 3]));
        }
    }
}

template <bool SORTED, bool BF16SRC>
__global__ __launch_bounds__(512, 8) void k_main(
    const float* __restrict__ x1f, const float* __restrict__ x1p,
    const float* __restrict__ x2f, const float* __restrict__ x2p,
    const char* __restrict__ xb1, const char* __restrict__ xb2,
    const char* __restrict__ wt,
    const int2* __restrict__ csr_sd,
    const int* __restrict__ edge_src, const int* __restrict__ edge_dst,
    float* __restrict__ out, int E) {
    __shared__ unsigned part[NROW][PROW];
    __shared__ int pdst[NROW];

    const int tid  = threadIdx.x;
    const int lane = tid & 63;
    const int wv   = tid >> 6;    // 0..7
    const int l31  = lane & 31;
    const int hh   = lane >> 5;
    const int r    = wv * 32 + l31;
    const int slot = blockIdx.x * TM + r;
    const bool ok  = slot < E;

    // init this wave's partial-slot dst markers (same-wave ordering suffices)
    if (lane == 0) { pdst[2 * wv] = -1; pdst[2 * wv + 1] = -1; }

    int d = -1, s = 0;
    if (ok) {
        if (SORTED) { int2 sd = csr_sd[slot]; s = sd.x; d = sd.y; }
        else        { d = edge_dst[slot]; s = edge_src[slot]; }
    }
    const int dg = (d < 0) ? 0 : d;
    const int sg = s;

    // ---- gather layer-1 B fragments straight into registers ----
    bf16x8 Bv[9];
    if (BF16SRC) {
        const char* bx2 = xb2 + (size_t)dg * (2 * FDIM);
        const char* bx1 = xb1 + (size_t)sg * (2 * FDIM);
#pragma unroll
        for (int ks = 0; ks < 4; ks++)
            Bv[ks] = *(const bf16x8*)(bx2 + (2 * ks + hh) * 16);
#pragma unroll
        for (int ks = 4; ks < 8; ks++)
            Bv[ks] = *(const bf16x8*)(bx1 + (2 * (ks - 4) + hh) * 16);
    } else {
        const float* fx2 = x2f + (size_t)dg * FDIM;
        const float* fx1 = x1f + (size_t)sg * FDIM;
#pragma unroll
        for (int ks = 0; ks < 8; ks++) {
            const float* b = (ks < 4) ? (fx2 + (2 * ks + hh) * 8)
                                      : (fx1 + (2 * (ks - 4) + hh) * 8);
            float4 a0 = *(const float4*)(b);
            float4 a1 = *(const float4*)(b + 4);
            union { unsigned u[4]; bf16x8 v; } B;
            B.u[0] = pack2(a0.x, a0.y); B.u[1] = pack2(a0.z, a0.w);
            B.u[2] = pack2(a1.x, a1.y); B.u[3] = pack2(a1.z, a1.w);
            Bv[ks] = B.v;
        }
    }
    {
        float dx = 0.f, dy = 0.f, dz = 0.f;
        if (ok) {
            dx = x1p[sg * 3 + 0] - x2p[dg * 3 + 0];
            dy = x1p[sg * 3 + 1] - x2p[dg * 3 + 1];
            dz = x1p[sg * 3 + 2] - x2p[dg * 3 + 2];
        }
        union { unsigned u[4]; bf16x8 v; } P;
        P.u[0] = hh ? 0u : pack2(dx, dy);
        P.u[1] = hh ? 0u : pack2(dz, 1.0f);   // feature 131 = 1.0 (bias multiplier)
        P.u[2] = 0u; P.u[3] = 0u;
        Bv[8] = P.v;
    }

    // ---- layer 1 (K=144, bias folded) ----
    unsigned pkA[32], pkB[32];
#pragma unroll
    for (int rt = 0; rt < 4; rt++) {
        const char* arow = wt + (rt * 32 + l31) * 32 + hh * 16;
        f32x16 acc = zerov();
#pragma unroll
        for (int ks = 0; ks < 9; ks++) {
            bf16x8 A = *(const bf16x8*)(arow + ks * CH);
            acc = __builtin_amdgcn_mfma_f32_32x32x16_bf16(A, Bv[ks], acc, 0, 0, 0);
        }
#pragma unroll
        for (int g = 0; g < 4; g++) {
            pkA[8 * rt + 2 * g + 0] = pack2(relu(acc[4 * g + 0]), relu(acc[4 * g + 1]));
            pkA[8 * rt + 2 * g + 1] = pack2(relu(acc[4 * g + 2]), relu(acc[4 * g + 3]));
        }
    }

    const unsigned biasw = hh ? 0u : 0x00003F80u;  // bf16 1.0 at feature 128
    layer_reg(wt + 9 * CH,  pkA, pkB, l31, hh, biasw);
    layer_reg(wt + 18 * CH, pkB, pkA, l31, hh, biasw);

    // ---- segmented max-scan over 32 edge-lanes, VALU-only via DPP ----
#define SCAN_STEP(CTRL, EXTRA)                                            \
    {                                                                     \
        int dsft = dppmov<CTRL>(d);                                       \
        bool take = (dsft == d) EXTRA;                                    \
        _Pragma("unroll")                                                 \
        for (int u = 0; u < 32; u++) {                                    \
            int sv = dppmov<CTRL>((int)pkA[u]);                           \
            unsigned mx = pmax2(pkA[u], (unsigned)sv);                    \
            pkA[u] = take ? mx : pkA[u];                                  \
        }                                                                 \
    }
    SCAN_STEP(0x111, )                      // row_shr:1
    SCAN_STEP(0x112, )                      // row_shr:2
    SCAN_STEP(0x114, )                      // row_shr:4
    SCAN_STEP(0x118, )                      // row_shr:8
    SCAN_STEP(0x142, && (l31 >= 16))        // row_bcast15
#undef SCAN_STEP

    // ---- flush: interior runs -> plain stores; boundary runs -> LDS partials ----
    const int dn = __shfl_down(d, 1, 32);
    const int dp = __shfl_up(d, 1, 32);
    unsigned long long startm = __ballot(dp != d) | 0x0000000100000001ull;
    const bool isflush = (d >= 0) && ((l31 == 31) || (dn != d));
    if (isflush) {
        unsigned long long below = startm & (~0ull >> (63 - lane));
        int sbit = 63 - __builtin_clzll(below);
        bool firstrun = ((sbit & 31) == 0);
        bool lastrun  = (l31 == 31);
        if (!firstrun && !lastrun) {
            float* orow = out + (size_t)d * HH;
#pragma unroll
            for (int g = 0; g < 16; g++) {
                const int F = 32 * (g >> 2) + 8 * (g & 3) + 4 * hh;
                unsigned w0 = pkA[2 * g], w1 = pkA[2 * g + 1];
                float4 v;
                v.x = __uint_as_float(w0 << 16);
                v.y = __uint_as_float(w0 & 0xffff0000u);
                v.z = __uint_as_float(w1 << 16);
                v.w = __uint_as_float(w1 & 0xffff0000u);
                *(float4*)(orow + F) = v;
            }
        } else {
            if (firstrun) {
                const int row = 2 * wv;
                pdst[row] = d;
#pragma unroll
                for (int g = 0; g < 16; g++)
                    *(uint2*)&part[row][32 * hh + 2 * g] = make_uint2(pkA[2 * g], pkA[2 * g + 1]);
            }
            if (lastrun) {
                const int row = 2 * wv + 1;
                pdst[row] = d;
#pragma unroll
                for (int g = 0; g < 16; g++)
                    *(uint2*)&part[row][32 * hh + 2 * g] = make_uint2(pkA[2 * g], pkA[2 * g + 1]);
            }
        }
    }
    __syncthreads();

    // ---- wave 0: chain-merge the 16 boundary partials ----
    if (wv == 0) {
        const int p  = lane;             // dword position 0..63
        const int u  = lane & 31;
        const int ph = lane >> 5;
        const int feat = 32 * (u >> 3) + 8 * ((u >> 1) & 3) + 4 * ph + 2 * (u & 1);
        int cur = -1, rs = 0;
        unsigned m = 0;
#pragma unroll
        for (int rr = 0; rr < NROW; rr++) {
            int dd = pdst[rr];
            if (dd != cur) {
                if (cur >= 0) {
                    float lo = __uint_as_float(m << 16);
                    float hi = __uint_as_float(m & 0xffff0000u);
                    if (rs == 0) {   // block-edge chain -> atomic
                        int* op = (int*)out + (size_t)cur * HH + feat;
                        if (lo > 0.f) atomicMax(op,     __float_as_int(lo));
                        if (hi > 0.f) atomicMax(op + 1, __float_as_int(hi));
                    } else {         // interior chain -> plain store
                        float2 v; v.x = lo; v.y = hi;
                        *(float2*)(out + (size_t)cur * HH + feat) = v;
                    }
                }
                cur = dd; rs = rr; m = 0;
            }
            if (dd >= 0) m = pmax2(m, part[rr][p]);
        }
        if (cur >= 0) {  // final chain is always a block-edge chain
            float lo = __uint_as_float(m << 16);
            float hi = __uint_as_float(m & 0xffff0000u);
            int* op = (int*)out + (size_t)cur * HH + feat;
            if (lo > 0.f) atomicMax(op,     __float_as_int(lo));
            if (hi > 0.f) atomicMax(op + 1, __float_as_int(hi));
        }
    }
}

extern "C" void kernel_launch(void* const* d_in, const int* in_sizes, int n_in,
                              void* d_out, int out_size, void* d_ws, size_t ws_size,
                              hipStream_t stream) {
    const float* x1f = (const float*)d_in[0];
    const float* x1p = (const float*)d_in[1];
    const float* x2f = (const float*)d_in[2];
    const float* x2p = (const float*)d_in[3];
    const float* W1  = (const float*)d_in[4];
    const float* b1  = (const float*)d_in[5];
    const float* W2  = (const float*)d_in[6];
    const float* b2  = (const float*)d_in[7];
    const float* W3  = (const float*)d_in[8];
    const float* b3  = (const float*)d_in[9];
    const int* esrc  = (const int*)d_in[10];
    const int* edst  = (const int*)d_in[11];
    const int E  = in_sizes[10];
    const int N1 = in_sizes[1] / 3;
    const int N2 = in_sizes[3] / 3;
    float* out = (float*)d_out;

    // workspace layout
    size_t off = 0;
    auto take = [&](size_t bytes) { size_t o = off; off = (off + bytes + 255) & ~(size_t)255; return o; };
    size_t o_cnt = take(4 * (size_t)N2);
    size_t o_cur = take(4 * (size_t)N2);
    size_t o_par = take(4 * 256);
    size_t o_csd = take(8 * (size_t)E);
    size_t o_wt  = take(2 * (size_t)WT_ELEMS);
    size_t need_csr = off;
    size_t o_x1  = take(2 * (size_t)N1 * FDIM);
    size_t o_x2  = take(2 * (size_t)N2 * FDIM);
    size_t need_bf = off;

    const int NB = (N2 + 1023) / 1024;
    bool use_csr = (need_csr <= ws_size) && (NB <= 256);
    bool use_bf  = (need_bf <= ws_size);

    char* ws = (char*)d_ws;
    unsigned short* wt = use_csr ? (unsigned short*)(ws + o_wt) : (unsigned short*)ws;
    int*  cnt    = (int*)(ws + o_cnt);
    int*  cursor = (int*)(ws + o_cur);
    int*  part   = (int*)(ws + o_par);
    int2* csr_sd = (int2*)(ws + o_csd);
    char* xb1    = ws + o_x1;
    char* xb2    = ws + o_x2;

    // output init: zero aggregate region, copy x2_pos into tail
    (void)hipMemsetAsync(out, 0, (size_t)N2 * HH * 4, stream);
    (void)hipMemcpyAsync(out + (size_t)N2 * HH, x2p, (size_t)N2 * 3 * 4,
                         hipMemcpyDeviceToDevice, stream);

    k_wprep<<<(WT_ELEMS + 255) / 256, 256, 0, stream>>>(W1, b1, W2, b2, W3, b3, wt);

    if (use_bf) {
        int n8_1 = N1 * FDIM / 8, n8_2 = N2 * FDIM / 8;
        k_cvt<<<(n8_1 + 255) / 256, 256, 0, stream>>>(x1f, (unsigned short*)xb1, n8_1);
        k_cvt<<<(n8_2 + 255) / 256, 256, 0, stream>>>(x2f, (unsigned short*)xb2, n8_2);
    }

    const int grid = (E + TM - 1) / TM;
    if (use_csr) {
        (void)hipMemsetAsync(cnt, 0, 4 * (size_t)N2, stream);
        k_hist<<<(E + 255) / 256, 256, 0, stream>>>(edst, cnt, E);
        k_scan_part<<<NB, 256, 0, stream>>>(cnt, part, N2);
        k_scan_top<<<1, 256, 0, stream>>>(part, NB);
        k_scan_down<<<NB, 256, 0, stream>>>(cnt, part, cursor, N2);
        k_fill<<<(E + 255) / 256, 256, 0, stream>>>(edst, esrc, cursor, csr_sd, E);
        if (use_bf)
            k_main<true, true><<<grid, 512, 0, stream>>>(
                x1f, x1p, x2f, x2p, xb1, xb2, (const char*)wt, csr_sd, esrc, edst, out, E);
        else
            k_main<true, false><<<grid, 512, 0, stream>>>(
                x1f, x1p, x2f, x2p, xb1, xb2, (const char*)wt, csr_sd, esrc, edst, out, E);
    } else {
        if (use_bf)
            k_main<false, true><<<grid, 512, 0, stream>>>(
                x1f, x1p, x2f, x2p, xb1, xb2, (const char*)wt, csr_sd, esrc, edst, out, E);
        else
            k_main<false, false><<<grid, 512, 0, stream>>>(
                x1f, x1p, x2f, x2p, xb1, xb2, (const char*)wt, csr_sd, esrc, edst, out, E);
    }
}

// Round 14
// 619.153 us; speedup vs baseline: 2.0887x; 2.0887x over previous
//
#include <hip/hip_runtime.h>
#include <hip/hip_bf16.h>

#define DEV __device__ __forceinline__

typedef short bf16x8 __attribute__((ext_vector_type(8)));
typedef float f32x16 __attribute__((ext_vector_type(16)));
typedef unsigned short u16x2 __attribute__((ext_vector_type(2)));

static constexpr int FDIM = 64;
static constexpr int HH   = 128;
static constexpr int NW   = 8;              // waves per block
static constexpr int TM   = NW * 32;        // 256 edges per block
static constexpr int CH   = 4096;           // weight chunk bytes: 128 n x 2 halves x 16B
static constexpr int NCH  = 27;             // 9 chunks x 3 layers (K=144, bias folded)
static constexpr int WT_ELEMS = NCH * 2048; // 55296 bf16 elements

static constexpr int PROW = 68;             // partial row stride (dwords, 272B: 64 data + pad)
static constexpr int NROW = 2 * NW;         // 16 partial rows

DEV unsigned pack2(float a, float b) {
    union { __hip_bfloat162 h; unsigned u; } cv;
    cv.h.x = __float2bfloat16(a);
    cv.h.y = __float2bfloat16(b);
    return cv.u;
}
DEV unsigned short f2bf(float f) {
    union { __hip_bfloat16 h; unsigned short u; } cv;
    cv.h = __float2bfloat16(f);
    return cv.u;
}
// packed bf16 max (valid for non-negative values: bit pattern is monotone)
DEV unsigned pmax2(unsigned a, unsigned b) {
    u16x2 av = __builtin_bit_cast(u16x2, a);
    u16x2 bv = __builtin_bit_cast(u16x2, b);
    return __builtin_bit_cast(unsigned, __builtin_elementwise_max(av, bv));
}
template <int CTRL>
DEV int dppmov(int x) {  // invalid lanes keep own value (old = x, bound_ctrl = false)
    return __builtin_amdgcn_update_dpp(x, x, CTRL, 0xf, 0xf, false);
}

// ---------------- input bf16 conversion ----------------
__global__ void k_cvt(const float* __restrict__ src, unsigned short* __restrict__ dst, int n8) {
    int i = blockIdx.x * 256 + threadIdx.x;
    if (i < n8) {
        float4 a = *(const float4*)(src + (size_t)i * 8);
        float4 b = *(const float4*)(src + (size_t)i * 8 + 4);
        uint4 o;
        o.x = pack2(a.x, a.y); o.y = pack2(a.z, a.w);
        o.z = pack2(b.x, b.y); o.w = pack2(b.z, b.w);
        *(uint4*)(dst + (size_t)i * 8) = o;
    }
}

// ---- weights -> chunk-major bf16 image (coalesced A-frag reads), bias folded ----
__global__ void k_wprep(const float* __restrict__ W1, const float* __restrict__ b1,
                        const float* __restrict__ W2, const float* __restrict__ b2,
                        const float* __restrict__ W3, const float* __restrict__ b3,
                        unsigned short* __restrict__ wt) {
    int i = blockIdx.x * 256 + threadIdx.x;
    if (i >= WT_ELEMS) return;
    int c = i >> 11, r = i & 2047;
    int n = r >> 4, half = (r >> 3) & 1, e = r & 7;
    int layer = c / 9, ks = c % 9;
    int k = ks * 16 + half * 8 + e;
    float v = 0.f;
    if (layer == 0) {
        if (k < 131) v = W1[k * HH + n];
        else if (k == 131) v = b1[n];        // msg feature 131 == 1.0
    } else {
        const float* W = (layer == 1) ? W2 : W3;
        const float* b = (layer == 1) ? b2 : b3;
        if (k < 128) v = W[k * HH + n];
        else if (k == 128) v = b[n];         // h feature 128 == 1.0
    }
    wt[i] = f2bf(v);
}

// ---------------- CSR build: hist -> scan -> fill ----------------
__global__ void k_hist(const int* __restrict__ edst, int* __restrict__ cnt, int E) {
    int e = blockIdx.x * 256 + threadIdx.x;
    if (e < E) atomicAdd(&cnt[edst[e]], 1);
}

__global__ void k_scan_part(const int* __restrict__ cnt, int* __restrict__ partial, int n2) {
    __shared__ int sm[256];
    int t = threadIdx.x;
    int base = blockIdx.x * 1024 + t * 4;
    int s = 0;
#pragma unroll
    for (int j = 0; j < 4; j++) { int idx = base + j; if (idx < n2) s += cnt[idx]; }
    sm[t] = s; __syncthreads();
    for (int off = 128; off > 0; off >>= 1) {
        if (t < off) sm[t] += sm[t + off];
        __syncthreads();
    }
    if (t == 0) partial[blockIdx.x] = sm[0];
}

__global__ void k_scan_top(int* __restrict__ partial, int nb) {
    __shared__ int sm[256];
    int t = threadIdx.x;
    int v = (t < nb) ? partial[t] : 0;
    sm[t] = v; __syncthreads();
    for (int off = 1; off < 256; off <<= 1) {
        int add = (t >= off) ? sm[t - off] : 0;
        __syncthreads();
        sm[t] += add;
        __syncthreads();
    }
    if (t < nb) partial[t] = sm[t] - v;   // exclusive
}

__global__ void k_scan_down(const int* __restrict__ cnt, const int* __restrict__ partial,
                            int* __restrict__ cursor, int n2) {
    __shared__ int sm[256];
    int t = threadIdx.x;
    int base = blockIdx.x * 1024 + t * 4;
    int c[4]; int s = 0;
#pragma unroll
    for (int j = 0; j < 4; j++) { int idx = base + j; c[j] = (idx < n2) ? cnt[idx] : 0; s += c[j]; }
    sm[t] = s; __syncthreads();
    for (int off = 1; off < 256; off <<= 1) {
        int add = (t >= off) ? sm[t - off] : 0;
        __syncthreads();
        sm[t] += add;
        __syncthreads();
    }
    int run = partial[blockIdx.x] + (sm[t] - s);
#pragma unroll
    for (int j = 0; j < 4; j++) {
        int idx = base + j;
        if (idx < n2) cursor[idx] = run;
        run += c[j];
    }
}

__global__ void k_fill(const int* __restrict__ edst, const int* __restrict__ esrc,
                       int* __restrict__ cursor, int2* __restrict__ csr_sd, int E) {
    int e = blockIdx.x * 256 + threadIdx.x;
    if (e < E) {
        int d = edst[e];
        int p = atomicAdd(&cursor[d], 1);
        csr_sd[p] = make_int2(esrc[e], d);
    }
}

// ---------------- register-resident MLP ----------------
DEV f32x16 zerov() {
    f32x16 v;
#pragma unroll
    for (int i = 0; i < 16; i++) v[i] = 0.f;
    return v;
}
DEV float relu(float x) { return fmaxf(x, 0.f); }

DEV void layer_reg(const char* __restrict__ wl, const unsigned pkin[32],
                   unsigned pkout[32], int l31, int hh, unsigned biasw) {
    unsigned xv[16];
#pragma unroll
    for (int ks = 0; ks < 8; ks++) {
        unsigned t0 = hh ? pkin[4 * ks + 0] : pkin[4 * ks + 2];
        unsigned t1 = hh ? pkin[4 * ks + 1] : pkin[4 * ks + 3];
        xv[2 * ks + 0] = (unsigned)__shfl_xor((int)t0, 32, 64);
        xv[2 * ks + 1] = (unsigned)__shfl_xor((int)t1, 32, 64);
    }
#pragma unroll
    for (int rt = 0; rt < 4; rt++) {
        const char* arow = wl + (rt * 32 + l31) * 32 + hh * 16;
        f32x16 acc = zerov();
#pragma unroll
        for (int ks = 0; ks < 8; ks++) {
            union { unsigned u[4]; bf16x8 v; } B;
            B.u[0] = hh ? xv[2 * ks + 0]   : pkin[4 * ks + 0];
            B.u[1] = hh ? xv[2 * ks + 1]   : pkin[4 * ks + 1];
            B.u[2] = hh ? pkin[4 * ks + 2] : xv[2 * ks + 0];
            B.u[3] = hh ? pkin[4 * ks + 3] : xv[2 * ks + 1];
            bf16x8 A = *(const bf16x8*)(arow + ks * CH);
            acc = __builtin_amdgcn_mfma_f32_32x32x16_bf16(A, B.v, acc, 0, 0, 0);
        }
        {   // ks = 8: bias row (feature 128 = 1.0)
            union { unsigned u[4]; bf16x8 v; } B;
            B.u[0] = biasw; B.u[1] = 0u; B.u[2] = 0u; B.u[3] = 0u;
            bf16x8 A = *(const bf16x8*)(arow + 8 * CH);
            acc = __builtin_amdgcn_mfma_f32_32x32x16_bf16(A, B.v, acc, 0, 0, 0);
        }
#pragma unroll
        for (int g = 0; g < 4; g++) {
            pkout[8 * rt + 2 * g + 0] = pack2(relu(acc[4 * g + 0]), relu(acc[4 * g + 1]));
            pkout[8 * rt + 2 * g + 1] = pack2(relu(acc[4 * g + 2]), relu(acc[4 * g + 3]));
        }
    }
}

template <bool SORTED, bool BF16SRC>
__global__ __launch_bounds__(512, 4) void k_main(
    const float* __restrict__ x1f, const float* __restrict__ x1p,
    const float* __restrict__ x2f, const float* __restrict__ x2p,
    const char* __restrict__ xb1, const char* __restrict__ xb2,
    const char* __restrict__ wt,
    const int2* __restrict__ csr_sd,
    const int* __restrict__ edge_src, const int* __restrict__ edge_dst,
    float* __restrict__ out, int E) {
    __shared__ unsigned part[NROW][PROW];
    __shared__ int pdst[NROW];

    const int tid  = threadIdx.x;
    const int lane = tid & 63;
    const int wv   = tid >> 6;    // 0..7
    const int l31  = lane & 31;
    const int hh   = lane >> 5;
    const int r    = wv * 32 + l31;
    const int slot = blockIdx.x * TM + r;
    const bool ok  = slot < E;

    // init this wave's partial-slot dst markers (same-wave ordering suffices)
    if (lane == 0) { pdst[2 * wv] = -1; pdst[2 * wv + 1] = -1; }

    int d = -1, s = 0;
    if (ok) {
        if (SORTED) { int2 sd = csr_sd[slot]; s = sd.x; d = sd.y; }
        else        { d = edge_dst[slot]; s = edge_src[slot]; }
    }
    const int dg = (d < 0) ? 0 : d;
    const int sg = s;

    // ---- gather layer-1 B fragments straight into registers ----
    bf16x8 Bv[9];
    if (BF16SRC) {
        const char* bx2 = xb2 + (size_t)dg * (2 * FDIM);
        const char* bx1 = xb1 + (size_t)sg * (2 * FDIM);
#pragma unroll
        for (int ks = 0; ks < 4; ks++)
            Bv[ks] = *(const bf16x8*)(bx2 + (2 * ks + hh) * 16);
#pragma unroll
        for (int ks = 4; ks < 8; ks++)
            Bv[ks] = *(const bf16x8*)(bx1 + (2 * (ks - 4) + hh) * 16);
    } else {
        const float* fx2 = x2f + (size_t)dg * FDIM;
        const float* fx1 = x1f + (size_t)sg * FDIM;
#pragma unroll
        for (int ks = 0; ks < 8; ks++) {
            const float* b = (ks < 4) ? (fx2 + (2 * ks + hh) * 8)
                                      : (fx1 + (2 * (ks - 4) + hh) * 8);
            float4 a0 = *(const float4*)(b);
            float4 a1 = *(const float4*)(b + 4);
            union { unsigned u[4]; bf16x8 v; } B;
            B.u[0] = pack2(a0.x, a0.y); B.u[1] = pack2(a0.z, a0.w);
            B.u[2] = pack2(a1.x, a1.y); B.u[3] = pack2(a1.z, a1.w);
            Bv[ks] = B.v;
        }
    }
    {
        float dx = 0.f, dy = 0.f, dz = 0.f;
        if (ok) {
            dx = x1p[sg * 3 + 0] - x2p[dg * 3 + 0];
            dy = x1p[sg * 3 + 1] - x2p[dg * 3 + 1];
            dz = x1p[sg * 3 + 2] - x2p[dg * 3 + 2];
        }
        union { unsigned u[4]; bf16x8 v; } P;
        P.u[0] = hh ? 0u : pack2(dx, dy);
        P.u[1] = hh ? 0u : pack2(dz, 1.0f);   // feature 131 = 1.0 (bias multiplier)
        P.u[2] = 0u; P.u[3] = 0u;
        Bv[8] = P.v;
    }

    // ---- layer 1 (K=144, bias folded) ----
    unsigned pkA[32], pkB[32];
#pragma unroll
    for (int rt = 0; rt < 4; rt++) {
        const char* arow = wt + (rt * 32 + l31) * 32 + hh * 16;
        f32x16 acc = zerov();
#pragma unroll
        for (int ks = 0; ks < 9; ks++) {
            bf16x8 A = *(const bf16x8*)(arow + ks * CH);
            acc = __builtin_amdgcn_mfma_f32_32x32x16_bf16(A, Bv[ks], acc, 0, 0, 0);
        }
#pragma unroll
        for (int g = 0; g < 4; g++) {
            pkA[8 * rt + 2 * g + 0] = pack2(relu(acc[4 * g + 0]), relu(acc[4 * g + 1]));
            pkA[8 * rt + 2 * g + 1] = pack2(relu(acc[4 * g + 2]), relu(acc[4 * g + 3]));
        }
    }

    const unsigned biasw = hh ? 0u : 0x00003F80u;  // bf16 1.0 at feature 128
    layer_reg(wt + 9 * CH,  pkA, pkB, l31, hh, biasw);
    layer_reg(wt + 18 * CH, pkB, pkA, l31, hh, biasw);

    // ---- segmented max-scan over 32 edge-lanes, VALU-only via DPP ----
#define SCAN_STEP(CTRL, EXTRA)                                            \
    {                                                                     \
        int dsft = dppmov<CTRL>(d);                                       \
        bool take = (dsft == d) EXTRA;                                    \
        _Pragma("unroll")                                                 \
        for (int u = 0; u < 32; u++) {                                    \
            int sv = dppmov<CTRL>((int)pkA[u]);                           \
            unsigned mx = pmax2(pkA[u], (unsigned)sv);                    \
            pkA[u] = take ? mx : pkA[u];                                  \
        }                                                                 \
    }
    SCAN_STEP(0x111, )                      // row_shr:1
    SCAN_STEP(0x112, )                      // row_shr:2
    SCAN_STEP(0x114, )                      // row_shr:4
    SCAN_STEP(0x118, )                      // row_shr:8
    SCAN_STEP(0x142, && (l31 >= 16))        // row_bcast15
#undef SCAN_STEP

    // ---- flush: interior runs -> plain stores; boundary runs -> LDS partials ----
    const int dn = __shfl_down(d, 1, 32);
    const int dp = __shfl_up(d, 1, 32);
    unsigned long long startm = __ballot(dp != d) | 0x0000000100000001ull;
    const bool isflush = (d >= 0) && ((l31 == 31) || (dn != d));
    if (isflush) {
        unsigned long long below = startm & (~0ull >> (63 - lane));
        int sbit = 63 - __builtin_clzll(below);
        bool firstrun = ((sbit & 31) == 0);
        bool lastrun  = (l31 == 31);
        if (!firstrun && !lastrun) {
            float* orow = out + (size_t)d * HH;
#pragma unroll
            for (int g = 0; g < 16; g++) {
                const int F = 32 * (g >> 2) + 8 * (g & 3) + 4 * hh;
                unsigned w0 = pkA[2 * g], w1 = pkA[2 * g + 1];
                float4 v;
                v.x = __uint_as_float(w0 << 16);
                v.y = __uint_as_float(w0 & 0xffff0000u);
                v.z = __uint_as_float(w1 << 16);
                v.w = __uint_as_float(w1 & 0xffff0000u);
                *(float4*)(orow + F) = v;
            }
        } else {
            if (firstrun) {
                const int row = 2 * wv;
                pdst[row] = d;
#pragma unroll
                for (int g = 0; g < 16; g++)
                    *(uint2*)&part[row][32 * hh + 2 * g] = make_uint2(pkA[2 * g], pkA[2 * g + 1]);
            }
            if (lastrun) {
                const int row = 2 * wv + 1;
                pdst[row] = d;
#pragma unroll
                for (int g = 0; g < 16; g++)
                    *(uint2*)&part[row][32 * hh + 2 * g] = make_uint2(pkA[2 * g], pkA[2 * g + 1]);
            }
        }
    }
    __syncthreads();

    // ---- wave 0: chain-merge the 16 boundary partials ----
    if (wv == 0) {
        const int p  = lane;             // dword position 0..63
        const int u  = lane & 31;
        const int ph = lane >> 5;
        const int feat = 32 * (u >> 3) + 8 * ((u >> 1) & 3) + 4 * ph + 2 * (u & 1);
        int cur = -1, rs = 0;
        unsigned m = 0;
#pragma unroll
        for (int rr = 0; rr < NROW; rr++) {
            int dd = pdst[rr];
            if (dd != cur) {
                if (cur >= 0) {
                    float lo = __uint_as_float(m << 16);
                    float hi = __uint_as_float(m & 0xffff0000u);
                    if (rs == 0) {   // block-edge chain -> atomic
                        int* op = (int*)out + (size_t)cur * HH + feat;
                        if (lo > 0.f) atomicMax(op,     __float_as_int(lo));
                        if (hi > 0.f) atomicMax(op + 1, __float_as_int(hi));
                    } else {         // interior chain -> plain store
                        float2 v; v.x = lo; v.y = hi;
                        *(float2*)(out + (size_t)cur * HH + feat) = v;
                    }
                }
                cur = dd; rs = rr; m = 0;
            }
            if (dd >= 0) m = pmax2(m, part[rr][p]);
        }
        if (cur >= 0) {  // final chain is always a block-edge chain
            float lo = __uint_as_float(m << 16);
            float hi = __uint_as_float(m & 0xffff0000u);
            int* op = (int*)out + (size_t)cur * HH + feat;
            if (lo > 0.f) atomicMax(op,     __float_as_int(lo));
            if (hi > 0.f) atomicMax(op + 1, __float_as_int(hi));
        }
    }
}

extern "C" void kernel_launch(void* const* d_in, const int* in_sizes, int n_in,
                              void* d_out, int out_size, void* d_ws, size_t ws_size,
                              hipStream_t stream) {
    const float* x1f = (const float*)d_in[0];
    const float* x1p = (const float*)d_in[1];
    const float* x2f = (const float*)d_in[2];
    const float* x2p = (const float*)d_in[3];
    const float* W1  = (const float*)d_in[4];
    const float* b1  = (const float*)d_in[5];
    const float* W2  = (const float*)d_in[6];
    const float* b2  = (const float*)d_in[7];
    const float* W3  = (const float*)d_in[8];
    const float* b3  = (const float*)d_in[9];
    const int* esrc  = (const int*)d_in[10];
    const int* edst  = (const int*)d_in[11];
    const int E  = in_sizes[10];
    const int N1 = in_sizes[1] / 3;
    const int N2 = in_sizes[3] / 3;
    float* out = (float*)d_out;

    // workspace layout
    size_t off = 0;
    auto take = [&](size_t bytes) { size_t o = off; off = (off + bytes + 255) & ~(size_t)255; return o; };
    size_t o_cnt = take(4 * (size_t)N2);
    size_t o_cur = take(4 * (size_t)N2);
    size_t o_par = take(4 * 256);
    size_t o_csd = take(8 * (size_t)E);
    size_t o_wt  = take(2 * (size_t)WT_ELEMS);
    size_t need_csr = off;
    size_t o_x1  = take(2 * (size_t)N1 * FDIM);
    size_t o_x2  = take(2 * (size_t)N2 * FDIM);
    size_t need_bf = off;

    const int NB = (N2 + 1023) / 1024;
    bool use_csr = (need_csr <= ws_size) && (NB <= 256);
    bool use_bf  = (need_bf <= ws_size);

    char* ws = (char*)d_ws;
    unsigned short* wt = use_csr ? (unsigned short*)(ws + o_wt) : (unsigned short*)ws;
    int*  cnt    = (int*)(ws + o_cnt);
    int*  cursor = (int*)(ws + o_cur);
    int*  part   = (int*)(ws + o_par);
    int2* csr_sd = (int2*)(ws + o_csd);
    char* xb1    = ws + o_x1;
    char* xb2    = ws + o_x2;

    // output init: zero aggregate region, copy x2_pos into tail
    (void)hipMemsetAsync(out, 0, (size_t)N2 * HH * 4, stream);
    (void)hipMemcpyAsync(out + (size_t)N2 * HH, x2p, (size_t)N2 * 3 * 4,
                         hipMemcpyDeviceToDevice, stream);

    k_wprep<<<(WT_ELEMS + 255) / 256, 256, 0, stream>>>(W1, b1, W2, b2, W3, b3, wt);

    if (use_bf) {
        int n8_1 = N1 * FDIM / 8, n8_2 = N2 * FDIM / 8;
        k_cvt<<<(n8_1 + 255) / 256, 256, 0, stream>>>(x1f, (unsigned short*)xb1, n8_1);
        k_cvt<<<(n8_2 + 255) / 256, 256, 0, stream>>>(x2f, (unsigned short*)xb2, n8_2);
    }

    const int grid = (E + TM - 1) / TM;
    if (use_csr) {
        (void)hipMemsetAsync(cnt, 0, 4 * (size_t)N2, stream);
        k_hist<<<(E + 255) / 256, 256, 0, stream>>>(edst, cnt, E);
        k_scan_part<<<NB, 256, 0, stream>>>(cnt, part, N2);
        k_scan_top<<<1, 256, 0, stream>>>(part, NB);
        k_scan_down<<<NB, 256, 0, stream>>>(cnt, part, cursor, N2);
        k_fill<<<(E + 255) / 256, 256, 0, stream>>>(edst, esrc, cursor, csr_sd, E);
        if (use_bf)
            k_main<true, true><<<grid, 512, 0, stream>>>(
                x1f, x1p, x2f, x2p, xb1, xb2, (const char*)wt, csr_sd, esrc, edst, out, E);
        else
            k_main<true, false><<<grid, 512, 0, stream>>>(
                x1f, x1p, x2f, x2p, xb1, xb2, (const char*)wt, csr_sd, esrc, edst, out, E);
    } else {
        if (use_bf)
            k_main<false, true><<<grid, 512, 0, stream>>>(
                x1f, x1p, x2f, x2p, xb1, xb2, (const char*)wt, csr_sd, esrc, edst, out, E);
        else
            k_main<false, false><<<grid, 512, 0, stream>>>(
                x1f, x1p, x2f, x2p, xb1, xb2, (const char*)wt, csr_sd, esrc, edst, out, E);
    }
}